// Round 3
// baseline (55.868 us; speedup 1.0000x reference)
//
#include <hip/hip_runtime.h>
#include <hip/hip_bf16.h>
#include <hip/hip_fp16.h>
#include <stdint.h>

// GGUF Q6_K fused dequant + GEMM:  out[16,14336] = x[16,4096] . W^T + bias
// Harness materializes uint8 w_q as int32 (one byte per dword, 192.7 MB).
// R3: NO LDS. Each lane loads its own row's ql/qh runs directly from global
// as uint2 (8B, guaranteed-aligned) with immediate offsets -- the byte->dword
// expansion makes per-lane runs contiguous dwords. Dequant per-dword SWAR ->
// bf16 -> mfma_f32_16x16x32_bf16 (M=16 batch, N=16 rows, K=32).
// K-split 8 via f32 atomicAdd onto bias-prefilled out.

#define OUT_F 14336
#define IN_F  4096
#define NB    16

using f32x4  = __attribute__((ext_vector_type(4))) float;
using short8 = __attribute__((ext_vector_type(8))) short;

constexpr int ROWS   = 64;                 // rows per 4-wave block (16 per wave)
constexpr int KSPLIT = 8;                  // k slices of 512 (2 super-blocks)

__device__ __forceinline__ uint32_t pack_bf16(float lo, float hi) {
  return (__builtin_bit_cast(uint32_t, lo) >> 16) |
         (__builtin_bit_cast(uint32_t, hi) & 0xffff0000u);
}

__global__ __launch_bounds__(256)
void prep_kernel(const float* __restrict__ x, const float* __restrict__ bias,
                 float* __restrict__ out, ushort* __restrict__ xbf, int use_ws)
{
  const int t = blockIdx.x * 256 + threadIdx.x;
  if (t < NB * OUT_F) {
    out[t] = bias[t % OUT_F];              // init out with bias; GEMM atomically adds
  }
  if (use_ws && t < NB * IN_F) {
    uint32_t u = __builtin_bit_cast(uint32_t, x[t]);
    xbf[t] = (ushort)((u + 0x8000u) >> 16); // f32 -> bf16
  }
}

template<bool USE_WS>
__global__ __launch_bounds__(256, 4)
void q6k_gemm(const int* __restrict__ wq,          // int32: one byte-value per dword
              const float* __restrict__ xf,
              const ushort* __restrict__ xbf,
              float* __restrict__ out)
{
  const int tid  = threadIdx.x;
  const int lane = tid & 63;
  const int wv   = tid >> 6;        // wave 0..3 -> 16 rows each
  const int l15  = lane & 15;       // row within wave / x batch-col
  const int lg   = lane >> 4;       // k-octet group 0..3
  const int hb   = lg >> 1;         // scale half-select
  const int by   = blockIdx.y;      // k split 0..7

  const int row = blockIdx.x * ROWS + wv * 16 + l15;
  // dword-unit base: row stride 3360 dwords, k-slice = 420 dwords (2 super-blocks)
  const int* base = wq + (size_t)row * 3360 + by * 420;
  const int k_blk = by * 512;

  f32x4 acc = {0.f, 0.f, 0.f, 0.f};

  #pragma unroll
  for (int sb = 0; sb < 2; ++sb) {
    const int* sbase = base + sb * 210;
    const uint2 dd = *(const uint2*)(sbase + 208);
    const float dsup = __half2float(
        __builtin_bit_cast(__half, (uint16_t)((dd.x & 0xffu) | ((dd.y & 0xffu) << 8))));
    const int k_sb = k_blk + sb * 256 + 8 * lg;

    #pragma unroll
    for (int m = 0; m < 8; ++m) {
      // 8-element run e0 = 32m + 8lg: ql dwords, qh dwords, one scale byte
      const int* qlp = sbase + (m >> 2) * 64 + (m & 1) * 32 + 8 * lg;
      const int* qhp = sbase + 128 + (m >> 2) * 32 + 8 * lg;
      const uint2 a0 = *(const uint2*)(qlp);
      const uint2 a1 = *(const uint2*)(qlp + 2);
      const uint2 a2 = *(const uint2*)(qlp + 4);
      const uint2 a3 = *(const uint2*)(qlp + 6);
      const uint2 b0 = *(const uint2*)(qhp);
      const uint2 b1 = *(const uint2*)(qhp + 2);
      const uint2 b2 = *(const uint2*)(qhp + 4);
      const uint2 b3 = *(const uint2*)(qhp + 6);
      const uint2 scp = *(const uint2*)(sbase + 192 + 2 * m);   // scales 2m, 2m+1

      const int sc = (int)(int8_t)(uint8_t)(hb ? scp.y : scp.x);
      const float dl  = dsup * (float)sc;
      const float mdl = -32.0f * dl;

      const int SL = 4 * ((m >> 1) & 1);
      const int SH = 2 * (m & 3);
      auto dq = [&](uint32_t q, uint32_t h) -> float {
        const uint32_t t = ((q >> SL) & 15u) | (((h >> SH) & 3u) << 4);
        return fmaf((float)t, dl, mdl);
      };

      union { short8 s; uint32_t u[4]; } bfr;
      bfr.u[0] = pack_bf16(dq(a0.x, b0.x), dq(a0.y, b0.y));
      bfr.u[1] = pack_bf16(dq(a1.x, b1.x), dq(a1.y, b1.y));
      bfr.u[2] = pack_bf16(dq(a2.x, b2.x), dq(a2.y, b2.y));
      bfr.u[3] = pack_bf16(dq(a3.x, b3.x), dq(a3.y, b3.y));

      short8 afrag;
      if constexpr (USE_WS) {
        afrag = *(const short8*)(xbf + (size_t)l15 * IN_F + k_sb + m * 32);
      } else {
        const float* xp = xf + (size_t)l15 * IN_F + k_sb + m * 32;
        const f32x4 v0 = *(const f32x4*)(xp);
        const f32x4 v1 = *(const f32x4*)(xp + 4);
        union { short8 s; uint32_t u[4]; } av;
        av.u[0] = pack_bf16(v0[0], v0[1]);
        av.u[1] = pack_bf16(v0[2], v0[3]);
        av.u[2] = pack_bf16(v1[0], v1[1]);
        av.u[3] = pack_bf16(v1[2], v1[3]);
        afrag = av.s;
      }

      acc = __builtin_amdgcn_mfma_f32_16x16x32_bf16(afrag, bfr.s, acc, 0, 0, 0);
    }
  }

  // C/D layout (m89-verified): col = lane&15 (output row), row = (lane>>4)*4 + reg (batch)
  #pragma unroll
  for (int r = 0; r < 4; ++r) {
    atomicAdd(&out[(size_t)(lg * 4 + r) * OUT_F + row], acc[r]);
  }
}

extern "C" void kernel_launch(void* const* d_in, const int* in_sizes, int n_in,
                              void* d_out, int out_size, void* d_ws, size_t ws_size,
                              hipStream_t stream)
{
  const float* x    = (const float*)d_in[0];
  const int*   wq   = (const int*)d_in[1];     // uint8 values materialized as int32
  const float* bias = (const float*)d_in[2];
  float*  out = (float*)d_out;
  ushort* xbf = (ushort*)d_ws;
  const bool use_ws = ws_size >= (size_t)NB * IN_F * 2;

  prep_kernel<<<dim3((NB * OUT_F + 255) / 256), dim3(256), 0, stream>>>(
      x, bias, out, xbf, use_ws ? 1 : 0);

  dim3 grid(OUT_F / ROWS, KSPLIT);
  if (use_ws) {
    q6k_gemm<true><<<grid, dim3(256), 0, stream>>>(wq, x, xbf, out);
  } else {
    q6k_gemm<false><<<grid, dim3(256), 0, stream>>>(wq, x, xbf, out);
  }
}